// Round 6
// baseline (1137.780 us; speedup 1.0000x reference)
//
#include <hip/hip_runtime.h>

typedef _Float16 half2v __attribute__((ext_vector_type(2)));

#define T_LEN 1024
#define NBATCH 1024
#define HID 20
#define G_BATCH 4

#if defined(__has_builtin)
#if __has_builtin(__builtin_amdgcn_fdot2)
#define HAVE_FDOT2 1
#endif
#endif

__device__ __forceinline__ float fdot2_(half2v a, half2v b, float c) {
#ifdef HAVE_FDOT2
    return __builtin_amdgcn_fdot2(a, b, c, false);
#else
    return c + (float)a[0] * (float)b[0] + (float)a[1] * (float)b[1];
#endif
}

__device__ __forceinline__ half2v pack2(float a, float b) {
    half2v r;
    r[0] = (_Float16)a;
    r[1] = (_Float16)b;
    return r;
}

__device__ __forceinline__ float tanh_s(float z) {
    return 2.0f / (1.0f + __expf(-2.0f * z)) - 1.0f;
}

// Load 20 f16 (one padded 24-half, 48B row, 16B-aligned) into 10 half2.
__device__ __forceinline__ void load_h20(const _Float16* row, half2v hp[10]) {
    uint4 q0 = *(const uint4*)(row);
    uint4 q1 = *(const uint4*)(row + 8);
    uint2 q2 = *(const uint2*)(row + 16);
    hp[0] = __builtin_bit_cast(half2v, q0.x);
    hp[1] = __builtin_bit_cast(half2v, q0.y);
    hp[2] = __builtin_bit_cast(half2v, q0.z);
    hp[3] = __builtin_bit_cast(half2v, q0.w);
    hp[4] = __builtin_bit_cast(half2v, q1.x);
    hp[5] = __builtin_bit_cast(half2v, q1.y);
    hp[6] = __builtin_bit_cast(half2v, q1.z);
    hp[7] = __builtin_bit_cast(half2v, q1.w);
    hp[8] = __builtin_bit_cast(half2v, q2.x);
    hp[9] = __builtin_bit_cast(half2v, q2.y);
}

// Layer-pipelined 3-wave block, G_BATCH=4 batch elements per block.
// Wave l owns layer l for ALL 4 batches; at superstep s it processes
// timestep t = s - l for each batch (4 independent recurrence chains,
// phase-interleaved for latency hiding). Weights shared across batches.
// Lanes 0..19 -> gates i(j),g(j); 20..39 -> f(j),o(j); 40..63 idle.
__global__ void __launch_bounds__(192, 1) lstm3_pipe4(
    const float* __restrict__ x,
    const float* __restrict__ wih0, const float* __restrict__ whh0,
    const float* __restrict__ bih0, const float* __restrict__ bhh0,
    const float* __restrict__ wih1, const float* __restrict__ whh1,
    const float* __restrict__ bih1, const float* __restrict__ bhh1,
    const float* __restrict__ wih2, const float* __restrict__ whh2,
    const float* __restrict__ bih2, const float* __restrict__ bhh2,
    const float* __restrict__ fcw, const float* __restrict__ fcb,
    float* __restrict__ out)
{
    __shared__ __align__(16) float xlds[G_BATCH * T_LEN];        // 16 KB
    __shared__ __align__(16) _Float16 rings[3][2][G_BATCH][24];  // 1152 B

    const int tid = threadIdx.x;
    const int wv = tid / 64;
    const int lane = tid & 63;
    const long b_base = (long)blockIdx.x * G_BATCH;

    // stage x: 4 contiguous rows = 4096 floats, coalesced float4
    {
        const float4* x4 = (const float4*)(x + b_base * T_LEN);
        float4* xl4 = (float4*)xlds;
        for (int i = tid; i < G_BATCH * T_LEN / 4; i += 192) xl4[i] = x4[i];
        for (int i = tid; i < 3 * 2 * G_BATCH * 24; i += 192)
            ((_Float16*)rings)[i] = (_Float16)0.0f;
    }

    const int j = (lane < 40) ? (lane % 20) : 0;
    const bool low = lane < 20;
    const int r0 = low ? j : (HID + j);                  // i-row / f-row
    const int r1 = low ? (2 * HID + j) : (3 * HID + j);  // g-row / o-row
    const int srcl = low ? lane : (lane - 20);

    // gate1 activation: tanh on g-lanes (low), sigmoid on o-lanes (high)
    const float kK = low ? -2.0f : -1.0f;
    const float kA = low ? 2.0f : 1.0f;
    const float kB = low ? -1.0f : 0.0f;

    const float* whh = (wv == 0) ? whh0 : (wv == 1) ? whh1 : whh2;
    const float* wih = (wv == 0) ? wih0 : (wv == 1) ? wih1 : wih2;
    const float* bih = (wv == 0) ? bih0 : (wv == 1) ? bih1 : bih2;
    const float* bhh = (wv == 0) ? bhh0 : (wv == 1) ? bhh1 : bhh2;

    half2v Whh[2][10];
    half2v Wih[2][10];
    float wx0 = 0.0f, wx1 = 0.0f;
    float bias0, bias1;
    {
#pragma unroll
        for (int k4 = 0; k4 < 5; ++k4) {
            float4 v0 = *(const float4*)(whh + r0 * HID + 4 * k4);
            Whh[0][2 * k4]     = pack2(v0.x, v0.y);
            Whh[0][2 * k4 + 1] = pack2(v0.z, v0.w);
            float4 v1 = *(const float4*)(whh + r1 * HID + 4 * k4);
            Whh[1][2 * k4]     = pack2(v1.x, v1.y);
            Whh[1][2 * k4 + 1] = pack2(v1.z, v1.w);
        }
        bias0 = bih[r0] + bhh[r0];
        bias1 = bih[r1] + bhh[r1];
        if (wv == 0) {
            wx0 = wih[r0];  // w_ih0 is (80,1)
            wx1 = wih[r1];
        } else {
#pragma unroll
            for (int k4 = 0; k4 < 5; ++k4) {
                float4 v0 = *(const float4*)(wih + r0 * HID + 4 * k4);
                Wih[0][2 * k4]     = pack2(v0.x, v0.y);
                Wih[0][2 * k4 + 1] = pack2(v0.z, v0.w);
                float4 v1 = *(const float4*)(wih + r1 * HID + 4 * k4);
                Wih[1][2 * k4]     = pack2(v1.x, v1.y);
                Wih[1][2 * k4 + 1] = pack2(v1.z, v1.w);
            }
        }
    }

    // Ring pointers by parity of even superstep (Round-4 scheme, verified):
    const int po_e = (1 - wv) & 1;   // own-read parity at even s
    const int pb_e = wv & 1;         // below-read / write parity at even s
    const _Float16* ro_e = &rings[wv][po_e][0][0];
    const _Float16* ro_o = &rings[wv][po_e ^ 1][0][0];
    const _Float16* rb_e = (wv > 0) ? &rings[wv - 1][pb_e][0][0] : ro_e;
    const _Float16* rb_o = (wv > 0) ? &rings[wv - 1][pb_e ^ 1][0][0] : ro_o;
    _Float16* wp_e = &rings[wv][pb_e][0][0];
    _Float16* wp_o = &rings[wv][pb_e ^ 1][0][0];

    float c[G_BATCH] = {0.f, 0.f, 0.f, 0.f};  // cell states (lanes 20..39)

    __syncthreads();  // x + rings visible

    // One superstep: t = s - wv for all G_BATCH batches, phase-interleaved.
    auto super = [&](int t, const _Float16* ro, const _Float16* rb,
                     _Float16* wp) {
        if (t < 0 || t >= T_LEN) return;  // wave-uniform

        // phase 1: issue ALL LDS loads (latencies overlap)
        half2v hown[G_BATCH][10];
#pragma unroll
        for (int g = 0; g < G_BATCH; ++g) load_h20(ro + g * 24, hown[g]);

        float pre0[G_BATCH], pre1[G_BATCH];
        if (wv == 0) {
#pragma unroll
            for (int g = 0; g < G_BATCH; ++g) {
                float d0 = 0.f, d1 = 0.f, e0 = 0.f, e1 = 0.f;
#pragma unroll
                for (int k = 0; k < 5; ++k) {
                    d0 = fdot2_(Whh[0][k],     hown[g][k],     d0);
                    d1 = fdot2_(Whh[0][k + 5], hown[g][k + 5], d1);
                    e0 = fdot2_(Whh[1][k],     hown[g][k],     e0);
                    e1 = fdot2_(Whh[1][k + 5], hown[g][k + 5], e1);
                }
                const float xt = xlds[g * T_LEN + t];
                pre0[g] = bias0 + (d0 + d1) + wx0 * xt;
                pre1[g] = bias1 + (e0 + e1) + wx1 * xt;
            }
        } else {
            half2v hbel[G_BATCH][10];
#pragma unroll
            for (int g = 0; g < G_BATCH; ++g) load_h20(rb + g * 24, hbel[g]);
#pragma unroll
            for (int g = 0; g < G_BATCH; ++g) {
                float d0 = 0.f, d1 = 0.f, e0 = 0.f, e1 = 0.f;
                float d2 = 0.f, d3 = 0.f, e2 = 0.f, e3 = 0.f;
#pragma unroll
                for (int k = 0; k < 5; ++k) {
                    d0 = fdot2_(Whh[0][k],     hown[g][k],     d0);
                    d1 = fdot2_(Whh[0][k + 5], hown[g][k + 5], d1);
                    e0 = fdot2_(Whh[1][k],     hown[g][k],     e0);
                    e1 = fdot2_(Whh[1][k + 5], hown[g][k + 5], e1);
                    d2 = fdot2_(Wih[0][k],     hbel[g][k],     d2);
                    d3 = fdot2_(Wih[0][k + 5], hbel[g][k + 5], d3);
                    e2 = fdot2_(Wih[1][k],     hbel[g][k],     e2);
                    e3 = fdot2_(Wih[1][k + 5], hbel[g][k + 5], e3);
                }
                pre0[g] = bias0 + (d0 + d1) + (d2 + d3);
                pre1[g] = bias1 + (e0 + e1) + (e2 + e3);
            }
        }

        // phase 3: activations (4 independent exp chains overlap)
        float a0[G_BATCH], a1[G_BATCH], u[G_BATCH];
#pragma unroll
        for (int g = 0; g < G_BATCH; ++g) {
            a0[g] = 1.0f / (1.0f + __expf(-pre0[g]));         // sig(i)/sig(f)
            a1[g] = kA / (1.0f + __expf(kK * pre1[g])) + kB;  // tanh(g)/sig(o)
            u[g] = a0[g] * a1[g];
        }
        // phase 4: cross-lane exchange (4 independent shfls overlap)
        float uf[G_BATCH];
#pragma unroll
        for (int g = 0; g < G_BATCH; ++g) uf[g] = __shfl(u[g], srcl, 64);

        // phase 5: cell update + h write (4 independent tanh chains overlap)
#pragma unroll
        for (int g = 0; g < G_BATCH; ++g) {
            float cn = a0[g] * c[g] + uf[g];       // a0 = sigma(f)
            float hn = a1[g] * tanh_s(cn);         // a1 = sigma(o)
            if (lane >= 20 && lane < 40) {
                c[g] = cn;
                wp[g * 24 + j] = (_Float16)hn;
            }
        }
    };

    for (int s = 0; s < T_LEN + 2; s += 2) {
        super(s - wv,     ro_e, rb_e, wp_e);
        __syncthreads();
        super(s + 1 - wv, ro_o, rb_o, wp_o);
        __syncthreads();
    }

    // FC epilogue: h2(T-1) at parity (T_LEN-1)&1 = 1; wave 2 owns it.
    if (wv == 2 && lane < 2 * G_BATCH) {
        const int g = lane >> 1, o = lane & 1;
        float acc = fcb[o];
        const _Float16* h2 = &rings[2][1][g][0];
#pragma unroll
        for (int k = 0; k < HID; ++k) {
            acc += fcw[o * HID + k] * (float)h2[k];
        }
        out[(b_base + g) * 2 + o] = acc;
    }
}

extern "C" void kernel_launch(void* const* d_in, const int* in_sizes, int n_in,
                              void* d_out, int out_size, void* d_ws, size_t ws_size,
                              hipStream_t stream) {
    const float* x    = (const float*)d_in[0];
    const float* wih0 = (const float*)d_in[1];
    const float* whh0 = (const float*)d_in[2];
    const float* bih0 = (const float*)d_in[3];
    const float* bhh0 = (const float*)d_in[4];
    const float* wih1 = (const float*)d_in[5];
    const float* whh1 = (const float*)d_in[6];
    const float* bih1 = (const float*)d_in[7];
    const float* bhh1 = (const float*)d_in[8];
    const float* wih2 = (const float*)d_in[9];
    const float* whh2 = (const float*)d_in[10];
    const float* bih2 = (const float*)d_in[11];
    const float* bhh2 = (const float*)d_in[12];
    const float* fcw  = (const float*)d_in[13];
    const float* fcb  = (const float*)d_in[14];

    lstm3_pipe4<<<dim3(NBATCH / G_BATCH), dim3(192), 0, stream>>>(
        x, wih0, whh0, bih0, bhh0,
        wih1, whh1, bih1, bhh1,
        wih2, whh2, bih2, bhh2,
        fcw, fcb, (float*)d_out);
}